// Round 2
// baseline (13737.386 us; speedup 1.0000x reference)
//
#include <hip/hip_runtime.h>
#include <math.h>

// Problem constants (fixed by the reference setup_inputs).
constexpr int N_NODES = 50000;
constexpr int IN_F    = 512;
constexpr int H_F     = 256;
constexpr int OUT_F   = 512;
constexpr int N_EDGE  = 800000;
constexpr int NDIM    = 4;
constexpr long NH     = (long)N_NODES * H_F;   // 12,800,000

#define LEAKY_SLOPE 0.01f

__device__ __forceinline__ float leaky_f(float v) { return v > 0.0f ? v : LEAKY_SLOPE * v; }

// ---------------------------------------------------------------------------
// Generic fp32 tiled GEMM: C = maybe_leaky(maybe_C + A @ B + maybe_bias)
// 64x64 tile, 256 threads, 4x4 per thread, K-tile 16. All row-major.
// ---------------------------------------------------------------------------
__global__ __launch_bounds__(256) void sgemm_kernel(
    const float* __restrict__ A, const float* __restrict__ B, float* __restrict__ C,
    const float* __restrict__ bias,
    int M, int N, int K, int lda, int ldb, int ldc,
    int accumulate, int leaky)
{
  __shared__ float As[16][68];   // [k][m]
  __shared__ float Bs[16][68];   // [k][n]

  const int tid = threadIdx.x;
  const int tx  = tid & 15;        // col group
  const int ty  = tid >> 4;        // row group
  const int row0 = blockIdx.x * 64;
  const int col0 = blockIdx.y * 64;

  // A-tile load mapping: 64 rows x 16 k, float4 per thread
  const int mA = tid >> 2;             // 0..63
  const int kA = (tid & 3) * 4;        // 0,4,8,12
  // B-tile load mapping: 16 k x 64 n, float4 per thread
  const int kB = tid >> 4;             // 0..15
  const int nB = (tid & 15) * 4;       // 0..60

  const int  rowA   = row0 + mA;
  const bool aValid = rowA < M;
  const long aRowOff = (long)rowA * lda;

  float acc[4][4] = {};

  for (int k0 = 0; k0 < K; k0 += 16) {
    float4 av = make_float4(0.f, 0.f, 0.f, 0.f);
    if (aValid) av = *(const float4*)(A + aRowOff + k0 + kA);
    As[kA + 0][mA] = av.x;
    As[kA + 1][mA] = av.y;
    As[kA + 2][mA] = av.z;
    As[kA + 3][mA] = av.w;

    float4 bv = *(const float4*)(B + (long)(k0 + kB) * ldb + col0 + nB);
    *(float4*)&Bs[kB][nB] = bv;

    __syncthreads();
    #pragma unroll
    for (int k = 0; k < 16; ++k) {
      float4 a4 = *(const float4*)&As[k][ty * 4];
      float4 b4 = *(const float4*)&Bs[k][tx * 4];
      float ar[4] = {a4.x, a4.y, a4.z, a4.w};
      float br[4] = {b4.x, b4.y, b4.z, b4.w};
      #pragma unroll
      for (int i = 0; i < 4; ++i)
        #pragma unroll
        for (int j = 0; j < 4; ++j)
          acc[i][j] = fmaf(ar[i], br[j], acc[i][j]);
    }
    __syncthreads();
  }

  float4 bvec = make_float4(0.f, 0.f, 0.f, 0.f);
  if (bias) bvec = *(const float4*)(bias + col0 + tx * 4);
  #pragma unroll
  for (int i = 0; i < 4; ++i) {
    int r = row0 + ty * 4 + i;
    if (r < M) {
      float* cp = C + (long)r * ldc + col0 + tx * 4;
      float4 o;
      o.x = acc[i][0] + bvec.x;
      o.y = acc[i][1] + bvec.y;
      o.z = acc[i][2] + bvec.z;
      o.w = acc[i][3] + bvec.w;
      if (accumulate) {
        float4 c = *(const float4*)cp;
        o.x += c.x; o.y += c.y; o.z += c.z; o.w += c.w;
      }
      if (leaky) { o.x = leaky_f(o.x); o.y = leaky_f(o.y); o.z = leaky_f(o.z); o.w = leaky_f(o.w); }
      *(float4*)cp = o;
    }
  }
}

// ---------------------------------------------------------------------------
// Degree / normalization helpers.  dinv is pre-scaled by sqrt(0.5) so that
// dinv_s*dinv_t == 0.5 * norm  (the ALPHA=0.5 within-weight is folded in).
// ---------------------------------------------------------------------------
__global__ void init_ones_kernel(float* __restrict__ p, int n)
{
  int i = blockIdx.x * 256 + threadIdx.x;
  if (i < n) p[i] = 1.0f;   // self-loop contributes 1 to every node's degree
}

__global__ void deg_count_kernel(const int* __restrict__ edges, float* __restrict__ deg,
                                 int E, int Nn)
{
  int i = blockIdx.x * 256 + threadIdx.x;   // over NDIM*E
  if (i >= NDIM * E) return;
  int d = i / E;
  int e = i - d * E;
  int t = edges[(long)d * 2 * E + E + e];   // dst
  atomicAdd(&deg[d * Nn + t], 1.0f);
}

__global__ void to_scaled_rsqrt_kernel(float* __restrict__ p, int n)
{
  int i = blockIdx.x * 256 + threadIdx.x;
  if (i < n) p[i] = sqrtf(0.5f / p[i]);     // deg >= 1 always (self-loops)
}

// WB[n][:] = 0.5*bias[:] + hw[n][:] * dinv[n]^2   (0.5*(bias + selfloop) term)
__global__ void init_wb_kernel(const float* __restrict__ hw, const float* __restrict__ dinv,
                               const float* __restrict__ bias, float* __restrict__ wb)
{
  int n = blockIdx.x;
  int lane = threadIdx.x;          // 64 lanes x float4 = 256 floats
  float di = dinv[n];
  float sl = di * di;              // = 0.5/deg
  float4 v = *(const float4*)(hw + (long)n * H_F + lane * 4);
  float4 b = *(const float4*)(bias + lane * 4);
  float4 o = make_float4(0.5f * b.x + v.x * sl, 0.5f * b.y + v.y * sl,
                         0.5f * b.z + v.z * sl, 0.5f * b.w + v.w * sl);
  *(float4*)(wb + (long)n * H_F + lane * 4) = o;
}

// One wave per edge: gather hw[src]*(0.5*norm), atomic-add into wb[dst].
__global__ __launch_bounds__(256) void scatter_kernel(
    const float* __restrict__ hw, const int* __restrict__ eidx,  // [2][E]
    const float* __restrict__ dinv, float* __restrict__ wb, int E)
{
  int e = blockIdx.x * 4 + (threadIdx.x >> 6);
  if (e >= E) return;
  int lane = threadIdx.x & 63;
  int s = eidx[e];
  int t = eidx[E + e];
  float norm = dinv[s] * dinv[t];     // includes the 0.5 factor
  float4 v = *(const float4*)(hw + (long)s * H_F + lane * 4);
  float* o = wb + (long)t * H_F + lane * 4;
  atomicAdd(o + 0, v.x * norm);
  atomicAdd(o + 1, v.y * norm);
  atomicAdd(o + 2, v.z * norm);
  atomicAdd(o + 3, v.w * norm);
}

// ---------------------------------------------------------------------------
// Attention: raw[a*4+b] = sum(T[a] .* P[b]);  att = softmax over a (per b)
// ---------------------------------------------------------------------------
__global__ void att_dot_kernel(const float* __restrict__ T, const float* __restrict__ P,
                               float* __restrict__ out16)
{
  const int a = blockIdx.x >> 2;
  const int b = blockIdx.x & 3;
  const float* ta = T + (long)a * (IN_F * H_F);
  const float* pb = P + (long)b * (IN_F * H_F);
  float s = 0.f;
  for (int i = threadIdx.x; i < IN_F * H_F; i += 256) s += ta[i] * pb[i];
  #pragma unroll
  for (int off = 32; off > 0; off >>= 1) s += __shfl_down(s, off, 64);
  __shared__ float red[4];
  if ((threadIdx.x & 63) == 0) red[threadIdx.x >> 6] = s;
  __syncthreads();
  if (threadIdx.x == 0) out16[blockIdx.x] = red[0] + red[1] + red[2] + red[3];
}

__global__ void att_softmax_kernel(const float* __restrict__ raw, float* __restrict__ att)
{
  int b = threadIdx.x;
  if (b < 4) {
    float r0 = raw[b], r1 = raw[4 + b], r2 = raw[8 + b], r3 = raw[12 + b];
    float m = fmaxf(fmaxf(r0, r1), fmaxf(r2, r3));
    float e0 = expf(r0 - m), e1 = expf(r1 - m), e2 = expf(r2 - m), e3 = expf(r3 - m);
    float inv = 1.0f / (e0 + e1 + e2 + e3);
    att[b] = e0 * inv; att[4 + b] = e1 * inv; att[8 + b] = e2 * inv; att[12 + b] = e3 * inv;
  }
}

// Wmix[a][h][o] = 0.5 * sum_b att[a*4+b] * invW[b*H+h][o]
__global__ void wmix_kernel(const float* __restrict__ invW, const float* __restrict__ att,
                            float* __restrict__ wmix)
{
  int i = blockIdx.x * 256 + threadIdx.x;
  if (i >= NDIM * H_F * OUT_F) return;
  int a   = i / (H_F * OUT_F);
  int rem = i - a * (H_F * OUT_F);      // = h*OUT_F + o
  float s = 0.f;
  #pragma unroll
  for (int b = 0; b < 4; ++b)
    s += att[a * 4 + b] * invW[(long)b * H_F * OUT_F + rem];
  wmix[i] = 0.5f * s;
}

// out[n][o] = invB[o]  (accumulator init)
__global__ void init_out_kernel(float* __restrict__ out, const float* __restrict__ invB)
{
  long i = (long)blockIdx.x * 256 + threadIdx.x;
  if (i < (long)N_NODES * OUT_F) out[i] = invB[i & (OUT_F - 1)];
}

// ---------------------------------------------------------------------------
extern "C" void kernel_launch(void* const* d_in, const int* in_sizes, int n_in,
                              void* d_out, int out_size, void* d_ws, size_t ws_size,
                              hipStream_t stream)
{
  const float* x     = (const float*)d_in[0];
  const int*   edges = (const int*)d_in[1];    // [4][2][E] int32
  const float* proj  = (const float*)d_in[2];  // [4][512][256]
  const float* gcnW  = (const float*)d_in[3];  // [4][256][256]
  const float* gcnB  = (const float*)d_in[4];  // [4][256]
  const float* bil   = (const float*)d_in[5];  // [256][256]
  const float* invW  = (const float*)d_in[6];  // [1024][512]
  const float* invB  = (const float*)d_in[7];  // [512]
  float* out = (float*)d_out;

  // Workspace layout (~158.6 MB): R | HWB | WB | dinv | T | att_raw | att | Wmix
  float* R       = (float*)d_ws;                   // NH
  float* HWB     = R + NH;                         // NH
  float* WB      = HWB + NH;                       // NH
  float* dinv    = WB + NH;                        // NDIM*N
  float* Tbuf    = dinv + NDIM * N_NODES;          // NDIM*IN_F*H_F
  float* att_raw = Tbuf + (long)NDIM * IN_F * H_F; // 16
  float* att     = att_raw + 16;                   // 16
  float* Wmix    = att + 16;                       // NDIM*H_F*OUT_F

  const int MB = (N_NODES + 63) / 64;              // 782

  // --- degrees -> scaled dinv (all dims) ---
  init_ones_kernel<<<(NDIM * N_NODES + 255) / 256, 256, 0, stream>>>(dinv, NDIM * N_NODES);
  deg_count_kernel<<<(NDIM * N_EDGE + 255) / 256, 256, 0, stream>>>(edges, dinv, N_EDGE, N_NODES);
  to_scaled_rsqrt_kernel<<<(NDIM * N_NODES + 255) / 256, 256, 0, stream>>>(dinv, NDIM * N_NODES);

  // --- attention: T[a] = P[a] @ bil; raw[a,b] = <T[a], P[b]>; softmax over a ---
  for (int a = 0; a < NDIM; ++a)
    sgemm_kernel<<<dim3(IN_F / 64, H_F / 64, 1), 256, 0, stream>>>(
        proj + (long)a * IN_F * H_F, bil, Tbuf + (long)a * IN_F * H_F, nullptr,
        IN_F, H_F, H_F, H_F, H_F, H_F, 0, 0);
  att_dot_kernel<<<16, 256, 0, stream>>>(Tbuf, proj, att_raw);
  att_softmax_kernel<<<1, 64, 0, stream>>>(att_raw, att);
  wmix_kernel<<<(NDIM * H_F * OUT_F + 255) / 256, 256, 0, stream>>>(invW, att, Wmix);

  // --- output accumulator = invB (broadcast) ---
  init_out_kernel<<<(int)(((long)N_NODES * OUT_F + 255) / 256), 256, 0, stream>>>(out, invB);

  // --- per-dim pipeline ---
  for (int d = 0; d < NDIM; ++d) {
    // R = leaky(x @ proj[d])
    sgemm_kernel<<<dim3(MB, H_F / 64, 1), 256, 0, stream>>>(
        x, proj + (long)d * IN_F * H_F, R, nullptr,
        N_NODES, H_F, IN_F, IN_F, H_F, H_F, 0, 1);
    // HWB = R @ gcnW[d]
    sgemm_kernel<<<dim3(MB, H_F / 64, 1), 256, 0, stream>>>(
        R, gcnW + (long)d * H_F * H_F, HWB, nullptr,
        N_NODES, H_F, H_F, H_F, H_F, H_F, 0, 0);
    // WB = 0.5*bias + selfloop   then scatter 0.5*norm*hw over edges
    init_wb_kernel<<<N_NODES, 64, 0, stream>>>(HWB, dinv + d * N_NODES,
                                               gcnB + d * H_F, WB);
    scatter_kernel<<<(N_EDGE + 3) / 4, 256, 0, stream>>>(
        HWB, edges + (long)d * 2 * N_EDGE, dinv + d * N_NODES, WB, N_EDGE);
    // out += WB @ invW[d*H:(d+1)*H, :]         (within, already 0.5-scaled)
    sgemm_kernel<<<dim3(MB, OUT_F / 64, 1), 256, 0, stream>>>(
        WB, invW + (long)d * H_F * OUT_F, out, nullptr,
        N_NODES, OUT_F, H_F, H_F, OUT_F, OUT_F, 1, 0);
    // out += R @ Wmix[d]                       (across, 0.5 folded into Wmix)
    sgemm_kernel<<<dim3(MB, OUT_F / 64, 1), 256, 0, stream>>>(
        R, Wmix + (long)d * H_F * OUT_F, out, nullptr,
        N_NODES, OUT_F, H_F, H_F, OUT_F, OUT_F, 1, (d == NDIM - 1) ? 1 : 0);
  }

  (void)in_sizes; (void)n_in; (void)out_size; (void)ws_size;
}

// Round 3
// 3828.032 us; speedup vs baseline: 3.5886x; 3.5886x over previous
//
#include <hip/hip_runtime.h>
#include <math.h>

// Problem constants (fixed by the reference setup_inputs).
constexpr int N_NODES = 50000;
constexpr int IN_F    = 512;
constexpr int H_F     = 256;
constexpr int OUT_F   = 512;
constexpr int N_EDGE  = 800000;
constexpr int NDIM    = 4;
constexpr long NH     = (long)N_NODES * H_F;   // 12,800,000

#define LEAKY_SLOPE 0.01f

__device__ __forceinline__ float leaky_f(float v) { return v > 0.0f ? v : LEAKY_SLOPE * v; }

// ---------------------------------------------------------------------------
// Generic fp32 tiled GEMM: C = maybe_leaky(maybe_C + A @ B + maybe_bias)
// 64x64 tile, 256 threads, 4x4 per thread, K-tile 16. All row-major.
// ---------------------------------------------------------------------------
__global__ __launch_bounds__(256) void sgemm_kernel(
    const float* __restrict__ A, const float* __restrict__ B, float* __restrict__ C,
    const float* __restrict__ bias,
    int M, int N, int K, int lda, int ldb, int ldc,
    int accumulate, int leaky)
{
  __shared__ float As[16][68];   // [k][m]
  __shared__ float Bs[16][68];   // [k][n]

  const int tid = threadIdx.x;
  const int tx  = tid & 15;        // col group
  const int ty  = tid >> 4;        // row group
  const int row0 = blockIdx.x * 64;
  const int col0 = blockIdx.y * 64;

  const int mA = tid >> 2;             // 0..63
  const int kA = (tid & 3) * 4;        // 0,4,8,12
  const int kB = tid >> 4;             // 0..15
  const int nB = (tid & 15) * 4;       // 0..60

  const int  rowA   = row0 + mA;
  const bool aValid = rowA < M;
  const long aRowOff = (long)rowA * lda;

  float acc[4][4] = {};

  for (int k0 = 0; k0 < K; k0 += 16) {
    float4 av = make_float4(0.f, 0.f, 0.f, 0.f);
    if (aValid) av = *(const float4*)(A + aRowOff + k0 + kA);
    As[kA + 0][mA] = av.x;
    As[kA + 1][mA] = av.y;
    As[kA + 2][mA] = av.z;
    As[kA + 3][mA] = av.w;

    float4 bv = *(const float4*)(B + (long)(k0 + kB) * ldb + col0 + nB);
    *(float4*)&Bs[kB][nB] = bv;

    __syncthreads();
    #pragma unroll
    for (int k = 0; k < 16; ++k) {
      float4 a4 = *(const float4*)&As[k][ty * 4];
      float4 b4 = *(const float4*)&Bs[k][tx * 4];
      float ar[4] = {a4.x, a4.y, a4.z, a4.w};
      float br[4] = {b4.x, b4.y, b4.z, b4.w};
      #pragma unroll
      for (int i = 0; i < 4; ++i)
        #pragma unroll
        for (int j = 0; j < 4; ++j)
          acc[i][j] = fmaf(ar[i], br[j], acc[i][j]);
    }
    __syncthreads();
  }

  float4 bvec = make_float4(0.f, 0.f, 0.f, 0.f);
  if (bias) bvec = *(const float4*)(bias + col0 + tx * 4);
  #pragma unroll
  for (int i = 0; i < 4; ++i) {
    int r = row0 + ty * 4 + i;
    if (r < M) {
      float* cp = C + (long)r * ldc + col0 + tx * 4;
      float4 o;
      o.x = acc[i][0] + bvec.x;
      o.y = acc[i][1] + bvec.y;
      o.z = acc[i][2] + bvec.z;
      o.w = acc[i][3] + bvec.w;
      if (accumulate) {
        float4 c = *(const float4*)cp;
        o.x += c.x; o.y += c.y; o.z += c.z; o.w += c.w;
      }
      if (leaky) { o.x = leaky_f(o.x); o.y = leaky_f(o.y); o.z = leaky_f(o.z); o.w = leaky_f(o.w); }
      *(float4*)cp = o;
    }
  }
}

// ---------------------------------------------------------------------------
// CSR build: count in-degrees (int), scan to row offsets, fill src buckets.
// ---------------------------------------------------------------------------
__global__ void deg_count_kernel(const int* __restrict__ edges, int* __restrict__ cnt, int E)
{
  int i = blockIdx.x * 256 + threadIdx.x;   // over NDIM*E
  if (i >= NDIM * E) return;
  int d = i / E;
  int e = i - d * E;
  int t = edges[(long)d * 2 * E + E + e];   // dst
  atomicAdd(&cnt[d * N_NODES + t], 1);
}

// One block per dim: exclusive scan of cnt -> row_start, and dinv = sqrt(0.5/(cnt+1)).
__global__ __launch_bounds__(1024) void scan_kernel(const int* __restrict__ cnt,
                                                    int* __restrict__ row_start,
                                                    float* __restrict__ dinv)
{
  const int d    = blockIdx.x;
  const int tid  = threadIdx.x;
  const int lane = tid & 63;
  const int wid  = tid >> 6;            // 16 waves
  __shared__ int wsum[16];
  __shared__ int carry_s;
  if (tid == 0) carry_s = 0;
  __syncthreads();

  for (int base = 0; base < N_NODES; base += 1024) {
    int i = base + tid;
    int v = (i < N_NODES) ? cnt[d * N_NODES + i] : 0;
    if (i < N_NODES) dinv[d * N_NODES + i] = sqrtf(0.5f / (float)(v + 1));

    int incl = v;
    #pragma unroll
    for (int off = 1; off < 64; off <<= 1) {
      int nb = __shfl_up(incl, off, 64);
      if (lane >= off) incl += nb;
    }
    if (lane == 63) wsum[wid] = incl;
    __syncthreads();
    if (wid == 0 && lane < 16) {
      int s = wsum[lane];
      #pragma unroll
      for (int off = 1; off < 16; off <<= 1) {
        int nb = __shfl_up(s, off, 16);
        if (lane >= off) s += nb;
      }
      wsum[lane] = s;                    // inclusive over waves
    }
    __syncthreads();
    int waveoff = (wid == 0) ? 0 : wsum[wid - 1];
    if (i < N_NODES) row_start[d * (N_NODES + 1) + i] = carry_s + waveoff + incl - v;
    __syncthreads();
    if (tid == 1023) carry_s += wsum[15];
    __syncthreads();
  }
  if (tid == 0) row_start[d * (N_NODES + 1) + N_NODES] = carry_s;   // == E
}

__global__ void fill_kernel(const int* __restrict__ edges, const int* __restrict__ row_start,
                            int* __restrict__ fill_cnt, int* __restrict__ csr_src, int E)
{
  int i = blockIdx.x * 256 + threadIdx.x;   // over NDIM*E
  if (i >= NDIM * E) return;
  int d = i / E;
  int e = i - d * E;
  int s = edges[(long)d * 2 * E + e];
  int t = edges[(long)d * 2 * E + E + e];
  int pos = row_start[d * (N_NODES + 1) + t] + atomicAdd(&fill_cnt[d * N_NODES + t], 1);
  csr_src[(long)d * E + pos] = s;
}

// ---------------------------------------------------------------------------
// Gather aggregation: one wave per dst node.
// WB[n] = 0.5*bias + dinv[n]^2 * hw[n] + sum_{s in CSR(n)} dinv[s]*dinv[n]*hw[s]
// ---------------------------------------------------------------------------
__global__ __launch_bounds__(256) void gather_aggr_kernel(
    const float* __restrict__ hw, const int* __restrict__ csr_src,
    const int* __restrict__ row_start, const float* __restrict__ dinv,
    const float* __restrict__ bias, float* __restrict__ wb)
{
  int n = blockIdx.x * 4 + (threadIdx.x >> 6);
  int lane = threadIdx.x & 63;
  float dt = dinv[n];
  float sl = dt * dt;                       // 0.5/deg
  float4 b = *(const float4*)(bias + lane * 4);
  float4 h = *(const float4*)(hw + (long)n * H_F + lane * 4);
  float4 acc = make_float4(0.5f * b.x + sl * h.x, 0.5f * b.y + sl * h.y,
                           0.5f * b.z + sl * h.z, 0.5f * b.w + sl * h.w);
  int beg = row_start[n];
  int end = row_start[n + 1];
  for (int j = beg; j < end; ++j) {
    int s = csr_src[j];
    float nm = dt * dinv[s];
    float4 v = *(const float4*)(hw + (long)s * H_F + lane * 4);
    acc.x = fmaf(nm, v.x, acc.x);
    acc.y = fmaf(nm, v.y, acc.y);
    acc.z = fmaf(nm, v.z, acc.z);
    acc.w = fmaf(nm, v.w, acc.w);
  }
  *(float4*)(wb + (long)n * H_F + lane * 4) = acc;
}

// ---------------------------------------------------------------------------
// Attention: raw[a*4+b] = sum(T[a] .* P[b]);  att = softmax over a (per b)
// ---------------------------------------------------------------------------
__global__ void att_dot_kernel(const float* __restrict__ T, const float* __restrict__ P,
                               float* __restrict__ out16)
{
  const int a = blockIdx.x >> 2;
  const int b = blockIdx.x & 3;
  const float* ta = T + (long)a * (IN_F * H_F);
  const float* pb = P + (long)b * (IN_F * H_F);
  float s = 0.f;
  for (int i = threadIdx.x; i < IN_F * H_F; i += 256) s += ta[i] * pb[i];
  #pragma unroll
  for (int off = 32; off > 0; off >>= 1) s += __shfl_down(s, off, 64);
  __shared__ float red[4];
  if ((threadIdx.x & 63) == 0) red[threadIdx.x >> 6] = s;
  __syncthreads();
  if (threadIdx.x == 0) out16[blockIdx.x] = red[0] + red[1] + red[2] + red[3];
}

__global__ void att_softmax_kernel(const float* __restrict__ raw, float* __restrict__ att)
{
  int b = threadIdx.x;
  if (b < 4) {
    float r0 = raw[b], r1 = raw[4 + b], r2 = raw[8 + b], r3 = raw[12 + b];
    float m = fmaxf(fmaxf(r0, r1), fmaxf(r2, r3));
    float e0 = expf(r0 - m), e1 = expf(r1 - m), e2 = expf(r2 - m), e3 = expf(r3 - m);
    float inv = 1.0f / (e0 + e1 + e2 + e3);
    att[b] = e0 * inv; att[4 + b] = e1 * inv; att[8 + b] = e2 * inv; att[12 + b] = e3 * inv;
  }
}

// Wmix[a][h][o] = 0.5 * sum_b att[a*4+b] * invW[b*H+h][o]
__global__ void wmix_kernel(const float* __restrict__ invW, const float* __restrict__ att,
                            float* __restrict__ wmix)
{
  int i = blockIdx.x * 256 + threadIdx.x;
  if (i >= NDIM * H_F * OUT_F) return;
  int a   = i / (H_F * OUT_F);
  int rem = i - a * (H_F * OUT_F);
  float s = 0.f;
  #pragma unroll
  for (int b = 0; b < 4; ++b)
    s += att[a * 4 + b] * invW[(long)b * H_F * OUT_F + rem];
  wmix[i] = 0.5f * s;
}

// out[n][o] = invB[o]  (accumulator init)
__global__ void init_out_kernel(float* __restrict__ out, const float* __restrict__ invB)
{
  long i = (long)blockIdx.x * 256 + threadIdx.x;
  if (i < (long)N_NODES * OUT_F) out[i] = invB[i & (OUT_F - 1)];
}

// ---------------------------------------------------------------------------
extern "C" void kernel_launch(void* const* d_in, const int* in_sizes, int n_in,
                              void* d_out, int out_size, void* d_ws, size_t ws_size,
                              hipStream_t stream)
{
  const float* x     = (const float*)d_in[0];
  const int*   edges = (const int*)d_in[1];    // [4][2][E] int32
  const float* proj  = (const float*)d_in[2];  // [4][512][256]
  const float* gcnW  = (const float*)d_in[3];  // [4][256][256]
  const float* gcnB  = (const float*)d_in[4];  // [4][256]
  const float* bil   = (const float*)d_in[5];  // [256][256]
  const float* invW  = (const float*)d_in[6];  // [1024][512]
  const float* invB  = (const float*)d_in[7];  // [512]
  float* out = (float*)d_out;

  // Workspace layout (~174 MB):
  float* R         = (float*)d_ws;                    // NH
  float* HWB       = R + NH;                          // NH
  float* WB        = HWB + NH;                        // NH
  float* dinv      = WB + NH;                         // NDIM*N
  float* Tbuf      = dinv + NDIM * N_NODES;           // NDIM*IN_F*H_F
  float* att_raw   = Tbuf + (long)NDIM * IN_F * H_F;  // 16
  float* att       = att_raw + 16;                    // 16
  float* Wmix      = att + 16;                        // NDIM*H_F*OUT_F
  int*   cnt       = (int*)(Wmix + (long)NDIM * H_F * OUT_F);  // NDIM*N
  int*   fill_cnt  = cnt + NDIM * N_NODES;            // NDIM*N (adjacent for one memset)
  int*   row_start = fill_cnt + NDIM * N_NODES;       // NDIM*(N+1)
  int*   csr_src   = row_start + NDIM * (N_NODES + 1);// NDIM*E

  const int MB = (N_NODES + 63) / 64;                 // 782

  // --- CSR build (all dims at once) ---
  hipMemsetAsync(cnt, 0, (size_t)2 * NDIM * N_NODES * sizeof(int), stream);
  deg_count_kernel<<<(NDIM * N_EDGE + 255) / 256, 256, 0, stream>>>(edges, cnt, N_EDGE);
  scan_kernel<<<NDIM, 1024, 0, stream>>>(cnt, row_start, dinv);
  fill_kernel<<<(NDIM * N_EDGE + 255) / 256, 256, 0, stream>>>(edges, row_start, fill_cnt,
                                                               csr_src, N_EDGE);

  // --- attention: T[a] = P[a] @ bil; raw[a,b] = <T[a], P[b]>; softmax over a ---
  for (int a = 0; a < NDIM; ++a)
    sgemm_kernel<<<dim3(IN_F / 64, H_F / 64, 1), 256, 0, stream>>>(
        proj + (long)a * IN_F * H_F, bil, Tbuf + (long)a * IN_F * H_F, nullptr,
        IN_F, H_F, H_F, H_F, H_F, H_F, 0, 0);
  att_dot_kernel<<<16, 256, 0, stream>>>(Tbuf, proj, att_raw);
  att_softmax_kernel<<<1, 64, 0, stream>>>(att_raw, att);
  wmix_kernel<<<(NDIM * H_F * OUT_F + 255) / 256, 256, 0, stream>>>(invW, att, Wmix);

  // --- output accumulator = invB (broadcast) ---
  init_out_kernel<<<(int)(((long)N_NODES * OUT_F + 255) / 256), 256, 0, stream>>>(out, invB);

  // --- per-dim pipeline ---
  for (int d = 0; d < NDIM; ++d) {
    // R = leaky(x @ proj[d])
    sgemm_kernel<<<dim3(MB, H_F / 64, 1), 256, 0, stream>>>(
        x, proj + (long)d * IN_F * H_F, R, nullptr,
        N_NODES, H_F, IN_F, IN_F, H_F, H_F, 0, 1);
    // HWB = R @ gcnW[d]
    sgemm_kernel<<<dim3(MB, H_F / 64, 1), 256, 0, stream>>>(
        R, gcnW + (long)d * H_F * H_F, HWB, nullptr,
        N_NODES, H_F, H_F, H_F, H_F, H_F, 0, 0);
    // WB = 0.5*bias + selfloop + sum_in 0.5*norm*hw[src]   (no atomics)
    gather_aggr_kernel<<<(N_NODES + 3) / 4, 256, 0, stream>>>(
        HWB, csr_src + (long)d * N_EDGE, row_start + d * (N_NODES + 1),
        dinv + d * N_NODES, gcnB + d * H_F, WB);
    // out += WB @ invW[d*H:(d+1)*H, :]         (within, already 0.5-scaled)
    sgemm_kernel<<<dim3(MB, OUT_F / 64, 1), 256, 0, stream>>>(
        WB, invW + (long)d * H_F * OUT_F, out, nullptr,
        N_NODES, OUT_F, H_F, H_F, OUT_F, OUT_F, 1, 0);
    // out += R @ Wmix[d]                       (across, 0.5 folded into Wmix)
    sgemm_kernel<<<dim3(MB, OUT_F / 64, 1), 256, 0, stream>>>(
        R, Wmix + (long)d * H_F * OUT_F, out, nullptr,
        N_NODES, OUT_F, H_F, H_F, OUT_F, OUT_F, 1, (d == NDIM - 1) ? 1 : 0);
  }

  (void)in_sizes; (void)n_in; (void)out_size; (void)ws_size;
}

// Round 4
// 2540.543 us; speedup vs baseline: 5.4073x; 1.5068x over previous
//
#include <hip/hip_runtime.h>
#include <math.h>

// Problem constants (fixed by the reference setup_inputs).
constexpr int N_NODES = 50000;
constexpr int IN_F    = 512;
constexpr int H_F     = 256;
constexpr int OUT_F   = 512;
constexpr int N_EDGE  = 800000;
constexpr int NDIM    = 4;
constexpr long NH     = (long)N_NODES * H_F;   // 12,800,000

#define LEAKY_SLOPE 0.01f

__device__ __forceinline__ float leaky_f(float v) { return v > 0.0f ? v : LEAKY_SLOPE * v; }

typedef __bf16 bf16x8 __attribute__((ext_vector_type(8)));
typedef float  f32x4  __attribute__((ext_vector_type(4)));

// ---------------------------------------------------------------------------
// Split-bf16 MFMA GEMM: C = maybe_leaky(maybe_C + A @ B)
// A fp32 (split hi/lo in staging), B pre-split bf16 in B^T [N][K] layout.
// 128x128 tile, 256 threads (4 waves, 2x2), 4x4 of 16x16x32 MFMA per wave,
// 3 MFMA per product (hh + hl + lh) for ~fp32 accuracy.
// A is chunked: k < kSplit reads A1, else A2 (for the fused [WB|R] epilogue).
// ---------------------------------------------------------------------------
__global__ __launch_bounds__(256) void mfma_gemm_kernel(
    const float* __restrict__ A1, const float* __restrict__ A2, int kSplit,
    const __bf16* __restrict__ BhT, const __bf16* __restrict__ BlT,
    float* __restrict__ C,
    int M, int N, int K, int lda1, int lda2, int ldc,
    int accumulate, int leaky)
{
  __shared__ __bf16 Ash[128][40];   // 32 k elems + 8 pad (80 B stride: 16B-aligned, conflict-free)
  __shared__ __bf16 Asl[128][40];
  __shared__ __bf16 Bsh[128][40];   // [n][k]
  __shared__ __bf16 Bsl[128][40];

  const int tid  = threadIdx.x;
  const int wid  = tid >> 6;
  const int lane = tid & 63;
  const int wm   = wid & 1;
  const int wn   = wid >> 1;
  const int row0 = blockIdx.x * 128;
  const int col0 = blockIdx.y * 128;
  const int l15  = lane & 15;
  const int quad = lane >> 4;

  // staging maps
  const int sAm = tid >> 3;          // 0..31 (4 passes of +32)
  const int sAk = (tid & 7) * 4;     // float4 within 32-k row
  const int sBn = tid >> 2;          // 0..63 (2 passes of +64)
  const int sBk = (tid & 3) * 8;     // 8 bf16 = 16 B

  f32x4 acc[4][4] = {};

  const int nkt = K >> 5;
  for (int kt = 0; kt < nkt; ++kt) {
    const float* Asrc; int lda; int k0;
    if (kt * 32 < kSplit) { Asrc = A1; lda = lda1; k0 = kt * 32; }
    else                  { Asrc = A2; lda = lda2; k0 = kt * 32 - kSplit; }

    __syncthreads();
    #pragma unroll
    for (int p = 0; p < 4; ++p) {
      int m = sAm + p * 32;
      int row = row0 + m;
      row = row < M ? row : M - 1;
      float4 v = *(const float4*)(Asrc + (long)row * lda + k0 + sAk);
      float f[4] = {v.x, v.y, v.z, v.w};
      union { __bf16 b[4]; short4 s; } h, l;
      #pragma unroll
      for (int i = 0; i < 4; ++i) {
        __bf16 hb = (__bf16)f[i];
        h.b[i] = hb;
        l.b[i] = (__bf16)(f[i] - (float)hb);
      }
      *(short4*)&Ash[m][sAk] = h.s;
      *(short4*)&Asl[m][sAk] = l.s;
    }
    #pragma unroll
    for (int p = 0; p < 2; ++p) {
      int n = sBn + p * 64;
      long off = (long)(col0 + n) * K + kt * 32 + sBk;
      *(int4*)&Bsh[n][sBk] = *(const int4*)(BhT + off);
      *(int4*)&Bsl[n][sBk] = *(const int4*)(BlT + off);
    }
    __syncthreads();

    bf16x8 ah[4], al[4], bh[4], bl[4];
    #pragma unroll
    for (int t = 0; t < 4; ++t) {
      ah[t] = *(const bf16x8*)&Ash[wm * 64 + t * 16 + l15][quad * 8];
      al[t] = *(const bf16x8*)&Asl[wm * 64 + t * 16 + l15][quad * 8];
      bh[t] = *(const bf16x8*)&Bsh[wn * 64 + t * 16 + l15][quad * 8];
      bl[t] = *(const bf16x8*)&Bsl[wn * 64 + t * 16 + l15][quad * 8];
    }
    #pragma unroll
    for (int mt = 0; mt < 4; ++mt)
      #pragma unroll
      for (int nt = 0; nt < 4; ++nt) {
        acc[mt][nt] = __builtin_amdgcn_mfma_f32_16x16x32_bf16(ah[mt], bh[nt], acc[mt][nt], 0, 0, 0);
        acc[mt][nt] = __builtin_amdgcn_mfma_f32_16x16x32_bf16(ah[mt], bl[nt], acc[mt][nt], 0, 0, 0);
        acc[mt][nt] = __builtin_amdgcn_mfma_f32_16x16x32_bf16(al[mt], bh[nt], acc[mt][nt], 0, 0, 0);
      }
  }

  // Epilogue: C/D layout col=lane&15, row=quad*4+reg
  #pragma unroll
  for (int mt = 0; mt < 4; ++mt)
    #pragma unroll
    for (int nt = 0; nt < 4; ++nt) {
      int col = col0 + wn * 64 + nt * 16 + l15;
      #pragma unroll
      for (int r = 0; r < 4; ++r) {
        int row = row0 + wm * 64 + mt * 16 + quad * 4 + r;
        if (row < M) {
          float* cp = C + (long)row * ldc + col;
          float v = acc[mt][nt][r];
          if (accumulate) v += *cp;
          if (leaky) v = leaky_f(v);
          *cp = v;
        }
      }
    }
}

// ---------------------------------------------------------------------------
// fp32 tiled GEMM (kept only for the tiny attention T = P @ bil GEMMs)
// ---------------------------------------------------------------------------
__global__ __launch_bounds__(256) void sgemm_kernel(
    const float* __restrict__ A, const float* __restrict__ B, float* __restrict__ C,
    int M, int N, int K, int lda, int ldb, int ldc)
{
  __shared__ float As[16][68];
  __shared__ float Bs[16][68];
  const int tid = threadIdx.x;
  const int tx  = tid & 15;
  const int ty  = tid >> 4;
  const int row0 = blockIdx.x * 64;
  const int col0 = blockIdx.y * 64;
  const int mA = tid >> 2;
  const int kA = (tid & 3) * 4;
  const int kB = tid >> 4;
  const int nB = (tid & 15) * 4;
  const int  rowA   = row0 + mA;
  const bool aValid = rowA < M;
  const long aRowOff = (long)rowA * lda;
  float acc[4][4] = {};
  for (int k0 = 0; k0 < K; k0 += 16) {
    float4 av = make_float4(0.f, 0.f, 0.f, 0.f);
    if (aValid) av = *(const float4*)(A + aRowOff + k0 + kA);
    As[kA + 0][mA] = av.x; As[kA + 1][mA] = av.y;
    As[kA + 2][mA] = av.z; As[kA + 3][mA] = av.w;
    float4 bv = *(const float4*)(B + (long)(k0 + kB) * ldb + col0 + nB);
    *(float4*)&Bs[kB][nB] = bv;
    __syncthreads();
    #pragma unroll
    for (int k = 0; k < 16; ++k) {
      float4 a4 = *(const float4*)&As[k][ty * 4];
      float4 b4 = *(const float4*)&Bs[k][tx * 4];
      float ar[4] = {a4.x, a4.y, a4.z, a4.w};
      float br[4] = {b4.x, b4.y, b4.z, b4.w};
      #pragma unroll
      for (int i = 0; i < 4; ++i)
        #pragma unroll
        for (int j = 0; j < 4; ++j)
          acc[i][j] = fmaf(ar[i], br[j], acc[i][j]);
    }
    __syncthreads();
  }
  #pragma unroll
  for (int i = 0; i < 4; ++i) {
    int r = row0 + ty * 4 + i;
    if (r < M)
      *(float4*)(C + (long)r * ldc + col0 + tx * 4) =
          make_float4(acc[i][0], acc[i][1], acc[i][2], acc[i][3]);
  }
}

// ---------------------------------------------------------------------------
// Weight prep: transpose + hi/lo split.  B:[Z][Kd][Nd] -> out:[Z][Nd][Kd]
// ---------------------------------------------------------------------------
__global__ void splitT_kernel(const float* __restrict__ B, __bf16* __restrict__ h,
                              __bf16* __restrict__ l, int Kd, int Nd, int total)
{
  int i = blockIdx.x * 256 + threadIdx.x;
  if (i >= total) return;
  int z   = i / (Kd * Nd);
  int rem = i - z * (Kd * Nd);
  int k = rem / Nd;
  int n = rem - k * Nd;
  float v = B[i];
  __bf16 hv = (__bf16)v;
  long o = (long)z * Kd * Nd + (long)n * Kd + k;
  h[o] = hv;
  l[o] = (__bf16)(v - (float)hv);
}

// BcatT[d][n][k] (k<H: invW[d*H+k][n]; else 0.5*sum_b att[d*4+b]*invW[b*H+(k-H)][n])
__global__ void bcat_kernel(const float* __restrict__ invW, const float* __restrict__ att,
                            __bf16* __restrict__ h, __bf16* __restrict__ l)
{
  int i = blockIdx.x * 256 + threadIdx.x;           // over 4*512*512
  if (i >= NDIM * OUT_F * 512) return;
  int d   = i >> 18;
  int rem = i & 262143;
  int n = rem >> 9;
  int k = rem & 511;
  float v;
  if (k < H_F) {
    v = invW[(long)(d * H_F + k) * OUT_F + n];
  } else {
    float s = 0.f;
    #pragma unroll
    for (int b = 0; b < 4; ++b)
      s += att[d * 4 + b] * invW[(long)(b * H_F + (k - H_F)) * OUT_F + n];
    v = 0.5f * s;
  }
  __bf16 hv = (__bf16)v;
  h[i] = hv;
  l[i] = (__bf16)(v - (float)hv);
}

// ---------------------------------------------------------------------------
// CSR build: count in-degrees, scan to row offsets, fill src buckets.
// ---------------------------------------------------------------------------
__global__ void deg_count_kernel(const int* __restrict__ edges, int* __restrict__ cnt, int E)
{
  int i = blockIdx.x * 256 + threadIdx.x;
  if (i >= NDIM * E) return;
  int d = i / E;
  int e = i - d * E;
  int t = edges[(long)d * 2 * E + E + e];
  atomicAdd(&cnt[d * N_NODES + t], 1);
}

__global__ __launch_bounds__(1024) void scan_kernel(const int* __restrict__ cnt,
                                                    int* __restrict__ row_start,
                                                    float* __restrict__ dinv)
{
  const int d    = blockIdx.x;
  const int tid  = threadIdx.x;
  const int lane = tid & 63;
  const int wid  = tid >> 6;
  __shared__ int wsum[16];
  __shared__ int carry_s;
  if (tid == 0) carry_s = 0;
  __syncthreads();
  for (int base = 0; base < N_NODES; base += 1024) {
    int i = base + tid;
    int v = (i < N_NODES) ? cnt[d * N_NODES + i] : 0;
    if (i < N_NODES) dinv[d * N_NODES + i] = sqrtf(0.5f / (float)(v + 1));
    int incl = v;
    #pragma unroll
    for (int off = 1; off < 64; off <<= 1) {
      int nb = __shfl_up(incl, off, 64);
      if (lane >= off) incl += nb;
    }
    if (lane == 63) wsum[wid] = incl;
    __syncthreads();
    if (wid == 0 && lane < 16) {
      int s = wsum[lane];
      #pragma unroll
      for (int off = 1; off < 16; off <<= 1) {
        int nb = __shfl_up(s, off, 16);
        if (lane >= off) s += nb;
      }
      wsum[lane] = s;
    }
    __syncthreads();
    int waveoff = (wid == 0) ? 0 : wsum[wid - 1];
    if (i < N_NODES) row_start[d * (N_NODES + 1) + i] = carry_s + waveoff + incl - v;
    __syncthreads();
    if (tid == 1023) carry_s += wsum[15];
    __syncthreads();
  }
  if (tid == 0) row_start[d * (N_NODES + 1) + N_NODES] = carry_s;
}

__global__ void fill_kernel(const int* __restrict__ edges, const int* __restrict__ row_start,
                            int* __restrict__ fill_cnt, int* __restrict__ csr_src, int E)
{
  int i = blockIdx.x * 256 + threadIdx.x;
  if (i >= NDIM * E) return;
  int d = i / E;
  int e = i - d * E;
  int s = edges[(long)d * 2 * E + e];
  int t = edges[(long)d * 2 * E + E + e];
  int pos = row_start[d * (N_NODES + 1) + t] + atomicAdd(&fill_cnt[d * N_NODES + t], 1);
  csr_src[(long)d * E + pos] = s;
}

// ---------------------------------------------------------------------------
// Gather aggregation: one wave per dst node (no atomics).
// ---------------------------------------------------------------------------
__global__ __launch_bounds__(256) void gather_aggr_kernel(
    const float* __restrict__ hw, const int* __restrict__ csr_src,
    const int* __restrict__ row_start, const float* __restrict__ dinv,
    const float* __restrict__ bias, float* __restrict__ wb)
{
  int n = blockIdx.x * 4 + (threadIdx.x >> 6);
  int lane = threadIdx.x & 63;
  float dt = dinv[n];
  float sl = dt * dt;
  float4 b = *(const float4*)(bias + lane * 4);
  float4 h = *(const float4*)(hw + (long)n * H_F + lane * 4);
  float4 acc = make_float4(0.5f * b.x + sl * h.x, 0.5f * b.y + sl * h.y,
                           0.5f * b.z + sl * h.z, 0.5f * b.w + sl * h.w);
  int beg = row_start[n];
  int end = row_start[n + 1];
  for (int j = beg; j < end; ++j) {
    int s = csr_src[j];
    float nm = dt * dinv[s];
    float4 v = *(const float4*)(hw + (long)s * H_F + lane * 4);
    acc.x = fmaf(nm, v.x, acc.x);
    acc.y = fmaf(nm, v.y, acc.y);
    acc.z = fmaf(nm, v.z, acc.z);
    acc.w = fmaf(nm, v.w, acc.w);
  }
  *(float4*)(wb + (long)n * H_F + lane * 4) = acc;
}

// ---------------------------------------------------------------------------
// Attention small kernels
// ---------------------------------------------------------------------------
__global__ void att_dot_kernel(const float* __restrict__ T, const float* __restrict__ P,
                               float* __restrict__ out16)
{
  const int a = blockIdx.x >> 2;
  const int b = blockIdx.x & 3;
  const float* ta = T + (long)a * (IN_F * H_F);
  const float* pb = P + (long)b * (IN_F * H_F);
  float s = 0.f;
  for (int i = threadIdx.x; i < IN_F * H_F; i += 256) s += ta[i] * pb[i];
  #pragma unroll
  for (int off = 32; off > 0; off >>= 1) s += __shfl_down(s, off, 64);
  __shared__ float red[4];
  if ((threadIdx.x & 63) == 0) red[threadIdx.x >> 6] = s;
  __syncthreads();
  if (threadIdx.x == 0) out16[blockIdx.x] = red[0] + red[1] + red[2] + red[3];
}

__global__ void att_softmax_kernel(const float* __restrict__ raw, float* __restrict__ att)
{
  int b = threadIdx.x;
  if (b < 4) {
    float r0 = raw[b], r1 = raw[4 + b], r2 = raw[8 + b], r3 = raw[12 + b];
    float m = fmaxf(fmaxf(r0, r1), fmaxf(r2, r3));
    float e0 = expf(r0 - m), e1 = expf(r1 - m), e2 = expf(r2 - m), e3 = expf(r3 - m);
    float inv = 1.0f / (e0 + e1 + e2 + e3);
    att[b] = e0 * inv; att[4 + b] = e1 * inv; att[8 + b] = e2 * inv; att[12 + b] = e3 * inv;
  }
}

__global__ void init_out_kernel(float* __restrict__ out, const float* __restrict__ invB)
{
  long i = (long)blockIdx.x * 256 + threadIdx.x;
  if (i < (long)N_NODES * OUT_F) out[i] = invB[i & (OUT_F - 1)];
}

// ---------------------------------------------------------------------------
extern "C" void kernel_launch(void* const* d_in, const int* in_sizes, int n_in,
                              void* d_out, int out_size, void* d_ws, size_t ws_size,
                              hipStream_t stream)
{
  const float* x     = (const float*)d_in[0];
  const int*   edges = (const int*)d_in[1];
  const float* proj  = (const float*)d_in[2];
  const float* gcnW  = (const float*)d_in[3];
  const float* gcnB  = (const float*)d_in[4];
  const float* bil   = (const float*)d_in[5];
  const float* invW  = (const float*)d_in[6];
  const float* invB  = (const float*)d_in[7];
  float* out = (float*)d_out;

  // Workspace layout (~180 MB)
  float* R         = (float*)d_ws;                    // NH
  float* HWB       = R + NH;                          // NH
  float* WB        = HWB + NH;                        // NH
  float* dinv      = WB + NH;                         // NDIM*N
  float* Tbuf      = dinv + NDIM * N_NODES;           // NDIM*IN_F*H_F
  float* att_raw   = Tbuf + (long)NDIM * IN_F * H_F;  // 16
  float* att       = att_raw + 16;                    // 16
  int*   cnt       = (int*)(att + 16);                // NDIM*N
  int*   fill_cnt  = cnt + NDIM * N_NODES;            // NDIM*N
  int*   row_start = fill_cnt + NDIM * N_NODES;       // NDIM*(N+1) = 200004
  int*   csr_src   = row_start + NDIM * (N_NODES + 1);// NDIM*E
  __bf16* projTh   = (__bf16*)(csr_src + (long)NDIM * N_EDGE);   // 4*256*512
  __bf16* projTl   = projTh + (long)NDIM * IN_F * H_F;
  __bf16* gcnWTh   = projTl + (long)NDIM * IN_F * H_F;           // 4*256*256
  __bf16* gcnWTl   = gcnWTh + (long)NDIM * H_F * H_F;
  __bf16* bcatTh   = gcnWTl + (long)NDIM * H_F * H_F;            // 4*512*512
  __bf16* bcatTl   = bcatTh + (long)NDIM * OUT_F * 512;

  const int MBL = (N_NODES + 127) / 128;              // 391

  // --- CSR build ---
  hipMemsetAsync(cnt, 0, (size_t)2 * NDIM * N_NODES * sizeof(int), stream);
  deg_count_kernel<<<(NDIM * N_EDGE + 255) / 256, 256, 0, stream>>>(edges, cnt, N_EDGE);
  scan_kernel<<<NDIM, 1024, 0, stream>>>(cnt, row_start, dinv);
  fill_kernel<<<(NDIM * N_EDGE + 255) / 256, 256, 0, stream>>>(edges, row_start, fill_cnt,
                                                               csr_src, N_EDGE);

  // --- weight prep (transpose + split) ---
  splitT_kernel<<<(NDIM * IN_F * H_F + 255) / 256, 256, 0, stream>>>(
      proj, projTh, projTl, IN_F, H_F, NDIM * IN_F * H_F);
  splitT_kernel<<<(NDIM * H_F * H_F + 255) / 256, 256, 0, stream>>>(
      gcnW, gcnWTh, gcnWTl, H_F, H_F, NDIM * H_F * H_F);

  // --- attention ---
  for (int a = 0; a < NDIM; ++a)
    sgemm_kernel<<<dim3(IN_F / 64, H_F / 64, 1), 256, 0, stream>>>(
        proj + (long)a * IN_F * H_F, bil, Tbuf + (long)a * IN_F * H_F,
        IN_F, H_F, H_F, H_F, H_F, H_F);
  att_dot_kernel<<<16, 256, 0, stream>>>(Tbuf, proj, att_raw);
  att_softmax_kernel<<<1, 64, 0, stream>>>(att_raw, att);
  bcat_kernel<<<(NDIM * OUT_F * 512 + 255) / 256, 256, 0, stream>>>(invW, att, bcatTh, bcatTl);

  // --- output accumulator = invB ---
  init_out_kernel<<<(int)(((long)N_NODES * OUT_F + 255) / 256), 256, 0, stream>>>(out, invB);

  // --- per-dim pipeline ---
  for (int d = 0; d < NDIM; ++d) {
    // R = leaky(x @ proj[d])      M=50000 N=256 K=512
    mfma_gemm_kernel<<<dim3(MBL, 2), 256, 0, stream>>>(
        x, x, IN_F, projTh + (long)d * IN_F * H_F, projTl + (long)d * IN_F * H_F, R,
        N_NODES, H_F, IN_F, IN_F, IN_F, H_F, 0, 1);
    // HWB = R @ gcnW[d]           M=50000 N=256 K=256
    mfma_gemm_kernel<<<dim3(MBL, 2), 256, 0, stream>>>(
        R, R, H_F, gcnWTh + (long)d * H_F * H_F, gcnWTl + (long)d * H_F * H_F, HWB,
        N_NODES, H_F, H_F, H_F, H_F, H_F, 0, 0);
    // WB = 0.5*bias + selfloop + neighbor gather
    gather_aggr_kernel<<<(N_NODES + 3) / 4, 256, 0, stream>>>(
        HWB, csr_src + (long)d * N_EDGE, row_start + d * (N_NODES + 1),
        dinv + d * N_NODES, gcnB + d * H_F, WB);
    // out += [WB | R] @ [invW_d ; Wmix_d]    M=50000 N=512 K=512 (kSplit=256)
    mfma_gemm_kernel<<<dim3(MBL, 4), 256, 0, stream>>>(
        WB, R, H_F, bcatTh + (long)d * OUT_F * 512, bcatTl + (long)d * OUT_F * 512, out,
        N_NODES, OUT_F, 512, H_F, H_F, OUT_F, 1, (d == NDIM - 1) ? 1 : 0);
  }

  (void)in_sizes; (void)n_in; (void)out_size; (void)ws_size;
}